// Round 12
// baseline (1977.484 us; speedup 1.0000x reference)
//
#include <hip/hip_runtime.h>

// Kernel ridge regression, RBF kernel. N=M=8192, D=32, gamma=1/32, reg=1e-3.
// R28 = R27 (validated 1710us, absmax 0.0556, NITER=94) + SCALAR-FOLDING
// BARRIER: the mu/rho global reduction and the alpha/beta recurrence are
// computed INSIDE the barrier's arrival tree, deleting the per-block wave0
// scalar phase (272 LLC loads + 2 double butterflies while 15 waves idle,
// ~1.2us/iter x 256 blocks redundant).
//  - arrival: thread0 f64-atomic-adds mu (and rho for the 16 sli==rbi
//    blocks -- these map to 16 DISTINCT group lines, no RMW pile-up) onto
//    its group line, waitcnt, then increments the arrival counter (same
//    add->waitcnt->publish idiom proven in R11-R26 barriers).
//  - group-last propagates group sums to the root line; root-last computes
//    alpha/beta ONCE, stores them as a single aligned u64 (untearable) +
//    recurrence state (rho_old/alpha_old) on the gen line, waitcnt, then
//    publishes gen. Spinners read the u64 after observing gen (publisher's
//    waitcnt orders ab before gen at the LLC coherence point).
//  - lazy resets (R26 parity scheme) now also zero the accumulator doubles;
//    identical parity-reuse safety proof (resets drain at the publisher's
//    next barrier entry waitcnt, before any same-parity arrival).
//  - mu/rho sum order becomes arrival-order (run-to-run nondeterministic,
//    ~1e-15 relative on alpha/beta); all blocks read the SAME published
//    values so replica consistency is preserved by construction. absmax
//    is no longer bit-pinned; expect ~0.0556 +/- 0.003.
// Lessons kept: hot loop and update phases untouched (R17/R19); square
// (16,16) decomposition (R21); contiguous qp writes (R22); pair-coop
// gather (R23); publish-first parity barrier (R26); NITER=94 EVEN (floor:
// 92 predicts 0.065 > 0.0644).

#define NN 8192
#define DD 32
#define REGL 1e-3f
#define NITER 94
#define NBLK 256
#define NSL 16   // slices (col panels)
#define NRB 16   // rowblocks
#define ROWS 512 // rows per block
#define COLS 512 // cols per block
#define NC2 (-0.045084220027780106f)  // -gamma*log2e
#define SCF (0.3002806023f)           // sqrt(2*gamma*log2e)

typedef short v8s __attribute__((ext_vector_type(8)));
typedef float v4f __attribute__((ext_vector_type(4)));

__device__ __forceinline__ float fast_exp2(float x) {
#if __has_builtin(__builtin_amdgcn_exp2f)
  return __builtin_amdgcn_exp2f(x);
#else
  float r;
  asm("v_exp_f32 %0, %1" : "=v"(r) : "v"(x));
  return r;
#endif
}

// ---- relaxed agent-scope coherent accessors ----
__device__ __forceinline__ float ld_f(const float* p) {
  return __hip_atomic_load(p, __ATOMIC_RELAXED, __HIP_MEMORY_SCOPE_AGENT);
}
__device__ __forceinline__ void st_f(float* p, float v) {
  __hip_atomic_store(p, v, __ATOMIC_RELAXED, __HIP_MEMORY_SCOPE_AGENT);
}
__device__ __forceinline__ double ld_d(const double* p) {
  return __hip_atomic_load(p, __ATOMIC_RELAXED, __HIP_MEMORY_SCOPE_AGENT);
}
__device__ __forceinline__ void st_d(double* p, double v) {
  __hip_atomic_store(p, v, __ATOMIC_RELAXED, __HIP_MEMORY_SCOPE_AGENT);
}

__device__ __forceinline__ ushort f2bf(float x) {  // RNE float->bf16 bits
  unsigned u = __float_as_uint(x);
  return (ushort)((u + 0x7fff + ((u >> 16) & 1)) >> 16);
}
__device__ __forceinline__ float bf2f(ushort b) {
  return __uint_as_float(((unsigned)b) << 16);
}

__device__ __forceinline__ double bfly64_d(double v) {
#pragma unroll
  for (int m = 1; m < 64; m <<= 1) v += __shfl_xor(v, m, 64);
  return v;
}
__device__ __forceinline__ double wave_down_sum_d(double v) {
#pragma unroll
  for (int off = 32; off > 0; off >>= 1) v += __shfl_down(v, off, 64);
  return v;
}

// Pair-cooperative 16-slot gather over qp[slot][row] (slot stride NN floats).
// (Validated R23; bitwise identical to the plain ascending 16-dword gather.)
__device__ __forceinline__ float gather16_pair(const float* qp, int rowpair,
                                               int e) {
  const double* qpd = (const double*)qp + (rowpair >> 1);
  float mine[8], recv[8];
#pragma unroll
  for (int k = 0; k < 8; ++k) {
    union {
      double d;
      float f[2];
    } u;
    u.d = ld_d(qpd + (size_t)(e * 8 + k) * (NN / 2));
    mine[k] = e ? u.f[1] : u.f[0];  // my row's value
    recv[k] = e ? u.f[0] : u.f[1];  // partner row's value (to exchange)
  }
#pragma unroll
  for (int k = 0; k < 8; ++k) recv[k] = __shfl_xor(recv[k], 1, 64);
  float s = 0.f;
#pragma unroll
  for (int k = 0; k < 8; ++k) s += e ? recv[k] : mine[k];
#pragma unroll
  for (int k = 0; k < 8; ++k) s += e ? mine[k] : recv[k];
  return s;
}

// ---- scalar-folding parity-double-buffered global barrier ----
// Layout (uints): parity p counters at bar + p*512:
//   group g line: [g*16+0]=counter, doubles at +2 (mu accum), +4 (rho accum)
//   root line:    [256]=counter, doubles at +258 (mu), +260 (rho)
// Shared gen line: [272]=gen, u64 ab at [274] (alpha lo, beta hi),
//   state doubles rho_old at [276], alpha_old at [278]. All 8B-aligned.
// scal=1: fold mu/rho partials up the tree; root-last computes alpha/beta,
// stores ab+state, waitcnt, publishes gen, then lazily resets counters AND
// accums of this parity (safe: parity reused 2 barriers later; resets drain
// at the publisher's next barrier entry waitcnt).
__device__ __forceinline__ void gbar_fold(unsigned* bar, int par, int scal,
                                          double mu_p, double rho_p,
                                          int addrho, float* s_ab) {
  __builtin_amdgcn_s_waitcnt(0);
  __syncthreads();
  if (threadIdx.x == 0) {
    unsigned* gen = bar + 272;
    unsigned long long* abp = (unsigned long long*)(bar + 274);
    double* st_rho = (double*)(bar + 276);
    double* st_alp = (double*)(bar + 278);
    unsigned* base = bar + (par << 9);
    double* gmu = (double*)(base + (blockIdx.x >> 4) * 16 + 2);
    double* grho = (double*)(base + (blockIdx.x >> 4) * 16 + 4);
    double* rmu = (double*)(base + 258);
    double* rrho = (double*)(base + 260);
    unsigned g =
        __hip_atomic_load(gen, __ATOMIC_RELAXED, __HIP_MEMORY_SCOPE_AGENT);
    if (scal) {
      __hip_atomic_fetch_add(gmu, mu_p, __ATOMIC_RELAXED,
                             __HIP_MEMORY_SCOPE_AGENT);
      if (addrho)
        __hip_atomic_fetch_add(grho, rho_p, __ATOMIC_RELAXED,
                               __HIP_MEMORY_SCOPE_AGENT);
      __atomic_signal_fence(__ATOMIC_SEQ_CST);
      __builtin_amdgcn_s_waitcnt(0);  // accum adds at LLC before counter add
      __atomic_signal_fence(__ATOMIC_SEQ_CST);
    }
    unsigned a = __hip_atomic_fetch_add(&base[(blockIdx.x >> 4) * 16], 1u,
                                        __ATOMIC_RELAXED,
                                        __HIP_MEMORY_SCOPE_AGENT);
    bool pub = false;
    float af = 0.f, bf = 0.f;
    bool have = false;
    if (a == 15u) {
      if (scal) {
        // all 16 members' adds precede their counter adds -> visible now
        double gm = ld_d(gmu), gr = ld_d(grho);
        __hip_atomic_fetch_add(rmu, gm, __ATOMIC_RELAXED,
                               __HIP_MEMORY_SCOPE_AGENT);
        if (gr != 0.0)
          __hip_atomic_fetch_add(rrho, gr, __ATOMIC_RELAXED,
                                 __HIP_MEMORY_SCOPE_AGENT);
        __atomic_signal_fence(__ATOMIC_SEQ_CST);
        __builtin_amdgcn_s_waitcnt(0);
        __atomic_signal_fence(__ATOMIC_SEQ_CST);
      }
      unsigned ra = __hip_atomic_fetch_add(base + 256, 1u, __ATOMIC_RELAXED,
                                           __HIP_MEMORY_SCOPE_AGENT);
      if (ra == 15u) {
        if (scal) {
          double m1 = ld_d(rmu), r1 = ld_d(rrho);
          double mu = m1 + (double)REGL * r1;  // r.(K+reg I)r
          bool first = (g == 0u);
          double rho_old = ld_d(st_rho), alpha_old = ld_d(st_alp);
          double beta_d = first ? 0.0 : r1 / rho_old;
          double alpha_d =
              first ? r1 / mu : r1 / (mu - r1 * beta_d / alpha_old);
          st_d(st_rho, r1);
          st_d(st_alp, alpha_d);
          af = (float)alpha_d;
          bf = (float)beta_d;
          have = true;
          unsigned long long pk =
              ((unsigned long long)__float_as_uint(bf) << 32) |
              (unsigned long long)__float_as_uint(af);
          __hip_atomic_store(abp, pk, __ATOMIC_RELAXED,
                             __HIP_MEMORY_SCOPE_AGENT);
        }
        __atomic_signal_fence(__ATOMIC_SEQ_CST);
        __builtin_amdgcn_s_waitcnt(0);  // ab/state at LLC before gen
        __atomic_signal_fence(__ATOMIC_SEQ_CST);
        __hip_atomic_store(gen, g + 1u, __ATOMIC_RELAXED,
                           __HIP_MEMORY_SCOPE_AGENT);
        pub = true;
        // lazy resets of this parity's counters and accumulators
#pragma unroll
        for (int k = 0; k < 16; ++k)
          __hip_atomic_store(&base[k * 16], 0u, __ATOMIC_RELAXED,
                             __HIP_MEMORY_SCOPE_AGENT);
        __hip_atomic_store(base + 256, 0u, __ATOMIC_RELAXED,
                           __HIP_MEMORY_SCOPE_AGENT);
        if (scal) {
#pragma unroll
          for (int k = 0; k < 16; ++k) {
            st_d((double*)(base + k * 16 + 2), 0.0);
            st_d((double*)(base + k * 16 + 4), 0.0);
          }
          st_d(rmu, 0.0);
          st_d(rrho, 0.0);
        }
      }
    }
    if (!pub) {
      unsigned t = 0;
      while (__hip_atomic_load(gen, __ATOMIC_RELAXED,
                               __HIP_MEMORY_SCOPE_AGENT) == g) {
        if (t < 64)
          __builtin_amdgcn_s_sleep(1);
        else
          __builtin_amdgcn_s_sleep(8);
        if (++t > (1u << 20)) break;  // escape hatch: fail, don't hang
      }
    }
    if (scal) {
      if (!have) {
        __atomic_signal_fence(__ATOMIC_SEQ_CST);
        unsigned long long pk = __hip_atomic_load(abp, __ATOMIC_RELAXED,
                                                  __HIP_MEMORY_SCOPE_AGENT);
        af = __uint_as_float((unsigned)(pk & 0xffffffffull));
        bf = __uint_as_float((unsigned)(pk >> 32));
      }
      s_ab[0] = af;
      s_ab[1] = bf;
    }
  }
  __atomic_signal_fence(__ATOMIC_SEQ_CST);
  __syncthreads();
}

// hi/lo bf16 fragment from global X: lane holds row `row`, k = kb..kb+7.
__device__ __forceinline__ void conv_frag(const float* __restrict__ X, int row,
                                          int kb, v8s& h, v8s& l) {
  const float4* rp = (const float4*)(X + (size_t)row * DD + kb);
  float4 f0 = rp[0], f1 = rp[1];
  float f[8] = {f0.x, f0.y, f0.z, f0.w, f1.x, f1.y, f1.z, f1.w};
  union {
    v8s v;
    ushort u[8];
  } H, L;
#pragma unroll
  for (int j = 0; j < 8; ++j) {
    float fs = SCF * f[j];
    ushort hb = f2bf(fs);
    H.u[j] = hb;
    L.u[j] = f2bf(fs - bf2f(hb));
  }
  h = H.v;
  l = L.v;
}

// ---------------- setup kernels ----------------

__global__ void setup_zero(unsigned* __restrict__ bar) {
  int i = blockIdx.x * 256 + threadIdx.x;
  if (i < 1024) bar[i] = 0u;
}

// stores NC2 * ||x||^2
__global__ void row_norms(const float* __restrict__ X, float* __restrict__ xx) {
  int i = blockIdx.x * blockDim.x + threadIdx.x;
  if (i < NN) {
    const float4* row = (const float4*)(X + (size_t)i * DD);
    float s = 0.f;
#pragma unroll
    for (int k = 0; k < DD / 4; ++k) {
      float4 v = row[k];
      s += v.x * v.x + v.y * v.y + v.z * v.z + v.w * v.w;
    }
    xx[i] = NC2 * s;
  }
}

// ---------------- matvec compute core (2 row-tiles / wave, 32 col-tiles) ---
__device__ __forceinline__ void mv_compute(const v8s* ah, const v8s* al,
                                           const ushort (*Bh)[512],
                                           const ushort (*Bl)[512],
                                           const float* Wj, int lane,
                                           float racc[2][4]) {
  const int n = lane & 15;
  for (int t = 0; t < 32; ++t) {
    v8s bh = *(const v8s*)&Bh[t][lane * 8];
    v8s bl = *(const v8s*)&Bl[t][lane * 8];
    float wn = Wj[t * 16 + n];
#pragma unroll
    for (int rs = 0; rs < 2; ++rs) {
      v4f c = {0.f, 0.f, 0.f, 0.f};
      c = __builtin_amdgcn_mfma_f32_16x16x32_bf16(al[rs], bh, c, 0, 0, 0);
      c = __builtin_amdgcn_mfma_f32_16x16x32_bf16(ah[rs], bl, c, 0, 0, 0);
      c = __builtin_amdgcn_mfma_f32_16x16x32_bf16(ah[rs], bh, c, 0, 0, 0);
#pragma unroll
      for (int u = 0; u < 4; ++u)
        racc[rs][u] = fmaf(fast_exp2(c[u]), wn, racc[rs][u]);
    }
  }
}

// ---------------- persistent CG-CG kernel ----------------
// Grid 256 blocks x 1024 threads: 16 rowblocks (512 rows) x 16 slices
// (512 cols). All CG vectors live in block-local LDS.

__global__ __launch_bounds__(1024, 4) void cg_persist(
    const float* __restrict__ Xtr, const float* __restrict__ Xte,
    const float* __restrict__ xx_tr, const float* __restrict__ xx_te,
    const float* __restrict__ y, float* __restrict__ qp0,
    float* __restrict__ qp1, unsigned* __restrict__ bar,
    float* __restrict__ out, int db) {
  __shared__ __align__(16) ushort Bh[32][512];
  __shared__ __align__(16) ushort Bl[32][512];
  __shared__ float Wj[512];
  __shared__ float Ebj[512];
  __shared__ float Erow[512];
  __shared__ float Rrow[512], Qrow[512];
  __shared__ float Rcol[512], Qcol[512], Pcol[512], Xcol[512];
  __shared__ double sredq[16];
  __shared__ double sredr[16];
  __shared__ float s_ab[2];  // alpha, beta

  const int tid = threadIdx.x;
  const int lane = tid & 63;
  const int wid = tid >> 6;
  const int n = lane & 15, q4 = lane >> 4;
  const int rbi = blockIdx.x & 15;
  const int sli = blockIdx.x >> 4;
  const int rowbase = rbi * ROWS;
  const int i0 = rowbase + wid * 32;
  const int jbase = sli * COLS;

  // ---- stage B-slice into LDS once: 512 cols x 32 k, hi/lo bf16 ----
#pragma unroll
  for (int rep = 0; rep < 2; ++rep) {
    int idx = rep * 1024 + tid;  // 0..2047 = (col, k-octet) pairs
    int c = idx & 511;
    int g = idx >> 9;  // k-octet 0..3
    int j = jbase + c;
    const float4* rp = (const float4*)(Xtr + (size_t)j * DD + g * 8);
    float4 f0 = rp[0], f1 = rp[1];
    float f[8] = {f0.x, f0.y, f0.z, f0.w, f1.x, f1.y, f1.z, f1.w};
    union {
      ushort u[8];
      uint4 qq;
    } H, L;
#pragma unroll
    for (int e = 0; e < 8; ++e) {
      float fs = SCF * f[e];
      ushort hb = f2bf(fs);
      H.u[e] = hb;
      L.u[e] = f2bf(fs - bf2f(hb));
    }
    int tile = c >> 4, cl = c & 15;
    int ln = cl + 16 * g;
    *(uint4*)&Bh[tile][ln * 8] = H.qq;
    *(uint4*)&Bl[tile][ln * 8] = L.qq;
  }
  if (tid < 512) {
    Ebj[tid] = fast_exp2(xx_tr[jbase + tid]);
    Erow[tid] = fast_exp2(xx_tr[rowbase + tid]);
    // ---- block-local CG state ----
    Rrow[tid] = y[rowbase + tid];
    Qrow[tid] = 0.f;
    Rcol[tid] = y[jbase + tid];
    Qcol[tid] = 0.f;
    Pcol[tid] = 0.f;
    Xcol[tid] = 0.f;
  }

  // ---- A fragments in registers, converted once ----
  v8s ah[2], al[2];
#pragma unroll
  for (int rs = 0; rs < 2; ++rs)
    conv_frag(Xtr, i0 + rs * 16 + n, q4 * 8, ah[rs], al[rs]);

  __syncthreads();

  for (int it = 0; it < NITER; ++it) {
    float* qp = (db && (it & 1)) ? qp1 : qp0;

    // 1. matvec input: Wj = r_k[cols] * col exp factor. Col-domain threads
    //    (the same ones that updated Rcol last iter -> same-thread dep).
    if (tid >= 512) {
      int ct = tid - 512;
      Wj[ct] = Rcol[ct] * Ebj[ct];
    }
    // 2. rho partial: r.r over this rowblock, computed by the 16 blocks
    //    with sli==rbi (they map to 16 DISTINCT barrier group lines, so
    //    their rho atomic-adds never pile on one line).
    if (sli == rbi) {
      float rvv = (tid < 512) ? Rrow[tid] : 0.f;
      double acc = wave_down_sum_d((double)rvv * (double)rvv);
      if (lane == 0) sredr[wid] = acc;
    }
    __syncthreads();

    // 3. matvec on r
    float racc[2][4] = {};
    mv_compute(ah, al, Bh, Bl, Wj, lane, racc);
#pragma unroll
    for (int rs = 0; rs < 2; ++rs)
#pragma unroll
      for (int u = 0; u < 4; ++u) {
#pragma unroll
        for (int m = 1; m < 16; m <<= 1)
          racc[rs][u] += __shfl_xor(racc[rs][u], m, 64);
      }
    double cmu = 0.0;
    if (n == 0) {
#pragma unroll
      for (int rs = 0; rs < 2; ++rs)
#pragma unroll
        for (int u = 0; u < 4; ++u) {
          int lrow = wid * 32 + rs * 16 + q4 * 4 + u;
          float qc = racc[rs][u] * Erow[lrow];  // (K r)_row, this slice
          st_f(&qp[(size_t)sli * NN + rowbase + lrow], qc);
          cmu += (double)qc * (double)Rrow[lrow];  // r.Kr partial
        }
    }
    cmu = bfly64_d(cmu);
    if (lane == 0) sredq[wid] = cmu;
    __syncthreads();

    // block-local partials for the barrier fold (thread0 only)
    double mu_part = 0.0, rho_part = 0.0;
    if (tid == 0) {
#pragma unroll
      for (int k3 = 0; k3 < 16; ++k3) mu_part += sredq[k3];
      if (sli == rbi) {
#pragma unroll
        for (int k3 = 0; k3 < 16; ++k3) rho_part += sredr[k3];
      }
    }

    // the ONE barrier: qp stores drained; mu/rho folded up the arrival
    // tree; alpha/beta published with gen and broadcast via s_ab.
    // Parity: db=1 -> it&1; db=0 -> 0 here, 1 at the B-barrier below.
    gbar_fold(bar, db ? (it & 1) : 0, 1, mu_part, rho_part, (sli == rbi),
              s_ab);
    const float alpha = s_ab[0], beta = s_ab[1];

    // 5+6. gather w = K r (+reg r) and update, SPLIT across thread domains:
    //    tid<512: rows; tid>=512: cols. Pair-cooperative loads; value order
    //    stays ascending slots 0..15 per row -> replicated values bitwise
    //    identical across blocks.
    if (tid < 512) {
      float s = gather16_pair(qp, rowbase + (tid & ~1), tid & 1);
      float wr = fmaf(REGL, Rrow[tid], s);
      float qn = fmaf(beta, Qrow[tid], wr);
      Qrow[tid] = qn;
      Rrow[tid] = fmaf(-alpha, qn, Rrow[tid]);
    } else {
      int ct = tid - 512;
      float s = gather16_pair(qp, jbase + (ct & ~1), ct & 1);
      float wc = fmaf(REGL, Rcol[ct], s);
      float qn = fmaf(beta, Qcol[ct], wc);
      Qcol[ct] = qn;
      float pn = fmaf(beta, Pcol[ct], Rcol[ct]);
      Pcol[ct] = pn;
      Xcol[ct] = fmaf(alpha, pn, Xcol[ct]);
      Rcol[ct] = fmaf(-alpha, qn, Rcol[ct]);
    }
    if (!db) gbar_fold(bar, 1, 0, 0.0, 0.0, 0, s_ab);  // protect qp, parity 1
    // db=1: cross-thread Rrow/Rcol reads next iter are covered by the
    // loop-top __syncthreads; qp reuse is protected by buffer alternation.
  }

  // ---- predict: out = K_test @ x, x = Xcol (block-local) ----
  {
    v8s th[2], tl[2];
#pragma unroll
    for (int rs = 0; rs < 2; ++rs)
      conv_frag(Xte, i0 + rs * 16 + n, q4 * 8, th[rs], tl[rs]);
    if (tid >= 512) {
      int ct = tid - 512;
      Wj[ct] = Xcol[ct] * Ebj[ct];  // same-thread dep on Xcol
    } else {
      Erow[tid] = fast_exp2(xx_te[rowbase + tid]);
    }
    __syncthreads();
    float racc[2][4] = {};
    mv_compute(th, tl, Bh, Bl, Wj, lane, racc);
#pragma unroll
    for (int rs = 0; rs < 2; ++rs)
#pragma unroll
      for (int u = 0; u < 4; ++u) {
#pragma unroll
        for (int m = 1; m < 16; m <<= 1)
          racc[rs][u] += __shfl_xor(racc[rs][u], m, 64);
      }
    if (n == 0) {
#pragma unroll
      for (int rs = 0; rs < 2; ++rs)
#pragma unroll
        for (int u = 0; u < 4; ++u) {
          int lrow = wid * 32 + rs * 16 + q4 * 4 + u;
          st_f(&qp0[(size_t)sli * NN + rowbase + lrow],
               racc[rs][u] * Erow[lrow]);
        }
    }
    // Predict barrier parity 0: db=1 ran NITER (even) alternating barriers
    // (last was parity 1) -> next is 0. db=0 ran NITER (0,1) pairs -> 0.
    gbar_fold(bar, 0, 0, 0.0, 0.0, 0, s_ab);
    if (sli == 0 && tid < 512) {
      const float* qb = qp0 + rowbase + tid;
      float s = 0.f;
#pragma unroll
      for (int s2 = 0; s2 < NSL; ++s2) s += ld_f(qb + (size_t)s2 * NN);
      out[rowbase + tid] = s;
    }
  }
}

// ---------------- launcher ----------------

extern "C" void kernel_launch(void* const* d_in, const int* in_sizes, int n_in,
                              void* d_out, int out_size, void* d_ws,
                              size_t ws_size, hipStream_t stream) {
  const float* X_train = (const float*)d_in[0];
  const float* y_train = (const float*)d_in[1];
  const float* X_test = (const float*)d_in[2];
  float* out = (float*)d_out;

  char* w = (char*)d_ws;
  size_t off = 0;
  float* xx_tr = (float*)(w + off); off += NN * 4;
  float* xx_te = (float*)(w + off); off += NN * 4;
  unsigned* bar = (unsigned*)(w + off); off += 4096;  // parity sets + gen/ab
  off = (off + 255) & ~(size_t)255;
  float* qp0 = (float*)(w + off); off += (size_t)NSL * NN * 4;  // 512KB
  size_t need0 = off;
  float* qp1 = (float*)(w + off); off += (size_t)NSL * NN * 4;  // 512KB
  size_t need1 = off;

  int db = (ws_size >= need1) ? 1 : 0;
  if (ws_size < need0) return;  // ~0.6MB; ws >= ~2.5MB proven (R13-R27 db)
  if (!db) qp1 = qp0;

  setup_zero<<<4, 256, 0, stream>>>(bar);
  row_norms<<<NN / 256, 256, 0, stream>>>(X_train, xx_tr);
  row_norms<<<NN / 256, 256, 0, stream>>>(X_test, xx_te);

  cg_persist<<<NBLK, 1024, 0, stream>>>(X_train, X_test, xx_tr, xx_te,
                                        y_train, qp0, qp1, bar, out, db);
}

// Round 13
// 1769.510 us; speedup vs baseline: 1.1175x; 1.1175x over previous
//
#include <hip/hip_runtime.h>

// Kernel ridge regression, RBF kernel. N=M=8192, D=32, gamma=1/32, reg=1e-3.
// R29 = exact revert to R27 (best validated: 1710us, absmax 0.05566406).
//
// R28 post-mortem (reverted): folding the mu/rho reduction into the
// barrier's arrival tree put f64 atomic RMWs (16-way per group line) +
// extra s_waitcnt(0) on the ARRIVAL critical path -> +2.8us/iter. Same
// failure class R16 fixed by per-block plain stores. Rule (4x measured:
// R17/R19/R22/R28): only touch structure that is (a) off the barrier
// arrival path, (b) free of RMW fan-in, (c) VMEM-liveness-neutral across
// mv_compute; and keep qp writes line-contiguous.
//
// Validated state: NITER=94 (absmax 0.0556 vs 0.0644 threshold; 92 would
// predict ~0.065 -> floor). NITER EVEN required (db=1 buffer alternation +
// predict-phase qp0 overwrite). Square 16x16 decomposition (R21), pair-
// cooperative gather (R23), publish-first parity barrier (R26).

#define NN 8192
#define DD 32
#define REGL 1e-3f
#define NITER 94
#define NBLK 256
#define NSL 16   // slices (col panels)
#define NRB 16   // rowblocks
#define ROWS 512 // rows per block
#define COLS 512 // cols per block
#define NC2 (-0.045084220027780106f)  // -gamma*log2e
#define SCF (0.3002806023f)           // sqrt(2*gamma*log2e)

typedef short v8s __attribute__((ext_vector_type(8)));
typedef float v4f __attribute__((ext_vector_type(4)));

__device__ __forceinline__ float fast_exp2(float x) {
#if __has_builtin(__builtin_amdgcn_exp2f)
  return __builtin_amdgcn_exp2f(x);
#else
  float r;
  asm("v_exp_f32 %0, %1" : "=v"(r) : "v"(x));
  return r;
#endif
}

// ---- relaxed agent-scope coherent accessors ----
__device__ __forceinline__ float ld_f(const float* p) {
  return __hip_atomic_load(p, __ATOMIC_RELAXED, __HIP_MEMORY_SCOPE_AGENT);
}
__device__ __forceinline__ void st_f(float* p, float v) {
  __hip_atomic_store(p, v, __ATOMIC_RELAXED, __HIP_MEMORY_SCOPE_AGENT);
}
__device__ __forceinline__ double ld_d(const double* p) {
  return __hip_atomic_load(p, __ATOMIC_RELAXED, __HIP_MEMORY_SCOPE_AGENT);
}
__device__ __forceinline__ void st_d(double* p, double v) {
  __hip_atomic_store(p, v, __ATOMIC_RELAXED, __HIP_MEMORY_SCOPE_AGENT);
}

__device__ __forceinline__ ushort f2bf(float x) {  // RNE float->bf16 bits
  unsigned u = __float_as_uint(x);
  return (ushort)((u + 0x7fff + ((u >> 16) & 1)) >> 16);
}
__device__ __forceinline__ float bf2f(ushort b) {
  return __uint_as_float(((unsigned)b) << 16);
}

__device__ __forceinline__ double bfly64_d(double v) {
#pragma unroll
  for (int m = 1; m < 64; m <<= 1) v += __shfl_xor(v, m, 64);
  return v;
}
__device__ __forceinline__ double wave_down_sum_d(double v) {
#pragma unroll
  for (int off = 32; off > 0; off >>= 1) v += __shfl_down(v, off, 64);
  return v;
}

// Pair-cooperative 16-slot gather over qp[slot][row] (slot stride NN floats).
// Threads with lane parity e=0/1 handle rows rowpair/rowpair+1. e=0 loads
// slots 0-7 as doubles (f[0]=row rowpair, f[1]=rowpair+1), e=1 loads slots
// 8-15. Off-row halves are exchanged via __shfl_xor(,1). Both parities sum
// their own row in ascending slot order 0..15 -> bitwise identical to the
// plain 16-dword ascending gather. (Validated R23.)
__device__ __forceinline__ float gather16_pair(const float* qp, int rowpair,
                                               int e) {
  const double* qpd = (const double*)qp + (rowpair >> 1);
  float mine[8], recv[8];
#pragma unroll
  for (int k = 0; k < 8; ++k) {
    union {
      double d;
      float f[2];
    } u;
    u.d = ld_d(qpd + (size_t)(e * 8 + k) * (NN / 2));
    mine[k] = e ? u.f[1] : u.f[0];  // my row's value
    recv[k] = e ? u.f[0] : u.f[1];  // partner row's value (to exchange)
  }
#pragma unroll
  for (int k = 0; k < 8; ++k) recv[k] = __shfl_xor(recv[k], 1, 64);
  // e==0: mine = slots 0-7, recv = slots 8-15 (both now my row)
  // e==1: recv = slots 0-7, mine = slots 8-15
  float s = 0.f;
#pragma unroll
  for (int k = 0; k < 8; ++k) s += e ? recv[k] : mine[k];
#pragma unroll
  for (int k = 0; k < 8; ++k) s += e ? mine[k] : recv[k];
  return s;
}

// ---- fence-free hierarchical global barrier, parity-double-buffered ----
// Counter set for parity p lives at bar + p*512: 16 group counters (stride
// 16, own lines) + root at +256. gen at bar[272] (own line, shared by both
// parities). Publisher stores gen FIRST, then lazily resets its parity's
// counters (safe: parity reused 2 barriers later; publisher's s_waitcnt(0)
// at its next gbarrier entry drains the resets before that barrier's
// publish can gate any same-parity arrival). (Validated R26.)
__device__ __forceinline__ void gbarrier(unsigned* bar, int par) {
  __builtin_amdgcn_s_waitcnt(0);
  __syncthreads();
  if (threadIdx.x == 0) {
    unsigned* gen = bar + 272;
    unsigned* base = bar + (par << 9);
    unsigned g =
        __hip_atomic_load(gen, __ATOMIC_RELAXED, __HIP_MEMORY_SCOPE_AGENT);
    unsigned a = __hip_atomic_fetch_add(&base[(blockIdx.x >> 4) * 16], 1u,
                                        __ATOMIC_RELAXED,
                                        __HIP_MEMORY_SCOPE_AGENT);
    bool pub = false;
    if (a == 15u) {
      unsigned ra = __hip_atomic_fetch_add(base + 256, 1u, __ATOMIC_RELAXED,
                                           __HIP_MEMORY_SCOPE_AGENT);
      if (ra == 15u) {
        // publish FIRST: waiters release immediately.
        __hip_atomic_store(gen, g + 1u, __ATOMIC_RELAXED,
                           __HIP_MEMORY_SCOPE_AGENT);
        pub = true;
        // lazy resets of this parity's counters.
#pragma unroll
        for (int k = 0; k < 16; ++k)
          __hip_atomic_store(&base[k * 16], 0u, __ATOMIC_RELAXED,
                             __HIP_MEMORY_SCOPE_AGENT);
        __hip_atomic_store(base + 256, 0u, __ATOMIC_RELAXED,
                           __HIP_MEMORY_SCOPE_AGENT);
      }
    }
    if (!pub) {
      unsigned t = 0;
      while (__hip_atomic_load(gen, __ATOMIC_RELAXED,
                               __HIP_MEMORY_SCOPE_AGENT) == g) {
        if (t < 64)
          __builtin_amdgcn_s_sleep(1);
        else
          __builtin_amdgcn_s_sleep(8);
        if (++t > (1u << 20)) break;  // escape hatch: fail, don't hang
      }
    }
  }
  __atomic_signal_fence(__ATOMIC_SEQ_CST);
  __syncthreads();
}

// hi/lo bf16 fragment from global X: lane holds row `row`, k = kb..kb+7.
__device__ __forceinline__ void conv_frag(const float* __restrict__ X, int row,
                                          int kb, v8s& h, v8s& l) {
  const float4* rp = (const float4*)(X + (size_t)row * DD + kb);
  float4 f0 = rp[0], f1 = rp[1];
  float f[8] = {f0.x, f0.y, f0.z, f0.w, f1.x, f1.y, f1.z, f1.w};
  union {
    v8s v;
    ushort u[8];
  } H, L;
#pragma unroll
  for (int j = 0; j < 8; ++j) {
    float fs = SCF * f[j];
    ushort hb = f2bf(fs);
    H.u[j] = hb;
    L.u[j] = f2bf(fs - bf2f(hb));
  }
  h = H.v;
  l = L.v;
}

// ---------------- setup kernels ----------------

__global__ void setup_zero(unsigned* __restrict__ bar) {
  int i = blockIdx.x * 256 + threadIdx.x;
  if (i < 1024) bar[i] = 0u;
}

// stores NC2 * ||x||^2
__global__ void row_norms(const float* __restrict__ X, float* __restrict__ xx) {
  int i = blockIdx.x * blockDim.x + threadIdx.x;
  if (i < NN) {
    const float4* row = (const float4*)(X + (size_t)i * DD);
    float s = 0.f;
#pragma unroll
    for (int k = 0; k < DD / 4; ++k) {
      float4 v = row[k];
      s += v.x * v.x + v.y * v.y + v.z * v.z + v.w * v.w;
    }
    xx[i] = NC2 * s;
  }
}

// ---------------- matvec compute core (2 row-tiles / wave, 32 col-tiles) ---
__device__ __forceinline__ void mv_compute(const v8s* ah, const v8s* al,
                                           const ushort (*Bh)[512],
                                           const ushort (*Bl)[512],
                                           const float* Wj, int lane,
                                           float racc[2][4]) {
  const int n = lane & 15;
  for (int t = 0; t < 32; ++t) {
    v8s bh = *(const v8s*)&Bh[t][lane * 8];
    v8s bl = *(const v8s*)&Bl[t][lane * 8];
    float wn = Wj[t * 16 + n];
#pragma unroll
    for (int rs = 0; rs < 2; ++rs) {
      v4f c = {0.f, 0.f, 0.f, 0.f};
      c = __builtin_amdgcn_mfma_f32_16x16x32_bf16(al[rs], bh, c, 0, 0, 0);
      c = __builtin_amdgcn_mfma_f32_16x16x32_bf16(ah[rs], bl, c, 0, 0, 0);
      c = __builtin_amdgcn_mfma_f32_16x16x32_bf16(ah[rs], bh, c, 0, 0, 0);
#pragma unroll
      for (int u = 0; u < 4; ++u)
        racc[rs][u] = fmaf(fast_exp2(c[u]), wn, racc[rs][u]);
    }
  }
}

// ---------------- persistent CG-CG kernel ----------------
// Grid 256 blocks x 1024 threads: 16 rowblocks (512 rows) x 16 slices
// (512 cols). All CG vectors live in block-local LDS.

__global__ __launch_bounds__(1024, 4) void cg_persist(
    const float* __restrict__ Xtr, const float* __restrict__ Xte,
    const float* __restrict__ xx_tr, const float* __restrict__ xx_te,
    const float* __restrict__ y, float* __restrict__ qp0,
    float* __restrict__ qp1, double* __restrict__ rho_s,
    double* __restrict__ mu_s, unsigned* __restrict__ bar,
    float* __restrict__ out, int db) {
  __shared__ __align__(16) ushort Bh[32][512];
  __shared__ __align__(16) ushort Bl[32][512];
  __shared__ float Wj[512];
  __shared__ float Ebj[512];
  __shared__ float Erow[512];
  __shared__ float Rrow[512], Qrow[512];
  __shared__ float Rcol[512], Qcol[512], Pcol[512], Xcol[512];
  __shared__ double sredq[16];
  __shared__ double sredr[16];
  __shared__ float s_ab[2];  // alpha, beta

  const int tid = threadIdx.x;
  const int lane = tid & 63;
  const int wid = tid >> 6;
  const int n = lane & 15, q4 = lane >> 4;
  const int rbi = blockIdx.x & 15;
  const int sli = blockIdx.x >> 4;
  const int rowbase = rbi * ROWS;
  const int i0 = rowbase + wid * 32;
  const int jbase = sli * COLS;

  // ---- stage B-slice into LDS once: 512 cols x 32 k, hi/lo bf16 ----
#pragma unroll
  for (int rep = 0; rep < 2; ++rep) {
    int idx = rep * 1024 + tid;  // 0..2047 = (col, k-octet) pairs
    int c = idx & 511;
    int g = idx >> 9;  // k-octet 0..3
    int j = jbase + c;
    const float4* rp = (const float4*)(Xtr + (size_t)j * DD + g * 8);
    float4 f0 = rp[0], f1 = rp[1];
    float f[8] = {f0.x, f0.y, f0.z, f0.w, f1.x, f1.y, f1.z, f1.w};
    union {
      ushort u[8];
      uint4 qq;
    } H, L;
#pragma unroll
    for (int e = 0; e < 8; ++e) {
      float fs = SCF * f[e];
      ushort hb = f2bf(fs);
      H.u[e] = hb;
      L.u[e] = f2bf(fs - bf2f(hb));
    }
    int tile = c >> 4, cl = c & 15;
    int ln = cl + 16 * g;
    *(uint4*)&Bh[tile][ln * 8] = H.qq;
    *(uint4*)&Bl[tile][ln * 8] = L.qq;
  }
  if (tid < 512) {
    Ebj[tid] = fast_exp2(xx_tr[jbase + tid]);
    Erow[tid] = fast_exp2(xx_tr[rowbase + tid]);
    // ---- block-local CG state ----
    Rrow[tid] = y[rowbase + tid];
    Qrow[tid] = 0.f;
    Rcol[tid] = y[jbase + tid];
    Qcol[tid] = 0.f;
    Pcol[tid] = 0.f;
    Xcol[tid] = 0.f;
  }

  // ---- A fragments in registers, converted once ----
  v8s ah[2], al[2];
#pragma unroll
  for (int rs = 0; rs < 2; ++rs)
    conv_frag(Xtr, i0 + rs * 16 + n, q4 * 8, ah[rs], al[rs]);

  double rho_old = 1.0, alpha_old = 1.0;  // wave-0 recurrence state
  __syncthreads();

  for (int it = 0; it < NITER; ++it) {
    float* qp = (db && (it & 1)) ? qp1 : qp0;

    // 1. matvec input: Wj = r_k[cols] * col exp factor. Col-domain threads
    //    (the same ones that updated Rcol last iter -> same-thread dep).
    if (tid >= 512) {
      int ct = tid - 512;
      Wj[ct] = Rcol[ct] * Ebj[ct];
    }
    // 2. rho partial (slice-0 blocks): r.r over this rowblock
    if (sli == 0) {
      float rvv = (tid < 512) ? Rrow[tid] : 0.f;
      double acc = wave_down_sum_d((double)rvv * (double)rvv);
      if (lane == 0) sredr[wid] = acc;
    }
    __syncthreads();
    if (sli == 0 && tid == 0) {
      double t = 0.0;
#pragma unroll
      for (int k3 = 0; k3 < 16; ++k3) t += sredr[k3];
      st_d(&rho_s[(size_t)it * 256 + rbi * 16], t);  // plain store, own line
    }

    // 3. matvec on r
    float racc[2][4] = {};
    mv_compute(ah, al, Bh, Bl, Wj, lane, racc);
#pragma unroll
    for (int rs = 0; rs < 2; ++rs)
#pragma unroll
      for (int u = 0; u < 4; ++u) {
#pragma unroll
        for (int m = 1; m < 16; m <<= 1)
          racc[rs][u] += __shfl_xor(racc[rs][u], m, 64);
      }
    double cmu = 0.0;
    if (n == 0) {
#pragma unroll
      for (int rs = 0; rs < 2; ++rs)
#pragma unroll
        for (int u = 0; u < 4; ++u) {
          int lrow = wid * 32 + rs * 16 + q4 * 4 + u;
          float qc = racc[rs][u] * Erow[lrow];  // (K r)_row, this slice
          st_f(&qp[(size_t)sli * NN + rowbase + lrow], qc);
          cmu += (double)qc * (double)Rrow[lrow];  // r.Kr partial
        }
    }
    cmu = bfly64_d(cmu);
    if (lane == 0) sredq[wid] = cmu;
    __syncthreads();
    if (tid == 0) {
      double t = 0.0;
#pragma unroll
      for (int k3 = 0; k3 < 16; ++k3) t += sredq[k3];
      st_d(&mu_s[(size_t)it * 256 + blockIdx.x], t);  // own slot, no RMW
    }

    // the ONE barrier: qp + rho + mu complete.
    // Parity: db=1 -> it&1 (one barrier/iter, alternates); db=0 -> 0 here
    // and 1 at the B-barrier below (strict 0,1,0,1 alternation).
    gbarrier(bar, db ? (it & 1) : 0);

    // 4. scalars via CG-CG recurrence (wave 0, then LDS broadcast);
    //    mu: 256 per-block slots reduced with 4 coalesced loads/lane.
    //    DO NOT reorder or interleave this phase (R17/R19/R28 lessons).
    if (wid == 0) {
      const double* mb = mu_s + (size_t)it * 256;
      double m = ld_d(mb + lane) + ld_d(mb + lane + 64) +
                 ld_d(mb + lane + 128) + ld_d(mb + lane + 192);
      double rv_l =
          (lane < 16) ? ld_d(rho_s + (size_t)it * 256 + lane * 16) : 0.0;
      double m1 = bfly64_d(m);
      double r1 = bfly64_d(rv_l);
      double mu = m1 + (double)REGL * r1;  // r.(K+reg I)r
      double beta_d = (it == 0) ? 0.0 : r1 / rho_old;
      double alpha_d =
          (it == 0) ? r1 / mu : r1 / (mu - r1 * beta_d / alpha_old);
      rho_old = r1;
      alpha_old = alpha_d;
      if (lane == 0) {
        s_ab[0] = (float)alpha_d;
        s_ab[1] = (float)beta_d;
      }
    }
    __syncthreads();
    const float alpha = s_ab[0], beta = s_ab[1];

    // 5+6. gather w = K r (+reg r) and update, SPLIT across thread domains:
    //    tid<512: rows; tid>=512: cols. Pair-cooperative loads; value order
    //    stays ascending slots 0..15 per row -> replicated values bitwise
    //    identical across blocks (and to R21/R23).
    if (tid < 512) {
      float s = gather16_pair(qp, rowbase + (tid & ~1), tid & 1);
      float wr = fmaf(REGL, Rrow[tid], s);
      float qn = fmaf(beta, Qrow[tid], wr);
      Qrow[tid] = qn;
      Rrow[tid] = fmaf(-alpha, qn, Rrow[tid]);
    } else {
      int ct = tid - 512;
      float s = gather16_pair(qp, jbase + (ct & ~1), ct & 1);
      float wc = fmaf(REGL, Rcol[ct], s);
      float qn = fmaf(beta, Qcol[ct], wc);
      Qcol[ct] = qn;
      float pn = fmaf(beta, Pcol[ct], Rcol[ct]);
      Pcol[ct] = pn;
      Xcol[ct] = fmaf(alpha, pn, Xcol[ct]);
      Rcol[ct] = fmaf(-alpha, qn, Rcol[ct]);
    }
    if (!db) gbarrier(bar, 1);  // single-buffer: protect qp (parity B=1)
    // db=1: cross-thread Rrow/Rcol reads next iter are covered by the
    // loop-top __syncthreads; qp reuse is protected by buffer alternation.
  }

  // ---- predict: out = K_test @ x, x = Xcol (block-local) ----
  {
    v8s th[2], tl[2];
#pragma unroll
    for (int rs = 0; rs < 2; ++rs)
      conv_frag(Xte, i0 + rs * 16 + n, q4 * 8, th[rs], tl[rs]);
    if (tid >= 512) {
      int ct = tid - 512;
      Wj[ct] = Xcol[ct] * Ebj[ct];  // same-thread dep on Xcol
    } else {
      Erow[tid] = fast_exp2(xx_te[rowbase + tid]);
    }
    __syncthreads();
    float racc[2][4] = {};
    mv_compute(th, tl, Bh, Bl, Wj, lane, racc);
#pragma unroll
    for (int rs = 0; rs < 2; ++rs)
#pragma unroll
      for (int u = 0; u < 4; ++u) {
#pragma unroll
        for (int m = 1; m < 16; m <<= 1)
          racc[rs][u] += __shfl_xor(racc[rs][u], m, 64);
      }
    if (n == 0) {
#pragma unroll
      for (int rs = 0; rs < 2; ++rs)
#pragma unroll
        for (int u = 0; u < 4; ++u) {
          int lrow = wid * 32 + rs * 16 + q4 * 4 + u;
          st_f(&qp0[(size_t)sli * NN + rowbase + lrow],
               racc[rs][u] * Erow[lrow]);
        }
    }
    // Predict barrier parity 0: db=1 ran NITER (even) alternating barriers
    // (last was parity 1) -> next is 0. db=0 ran NITER (0,1) pairs -> 0.
    gbarrier(bar, 0);
    if (sli == 0 && tid < 512) {
      const float* qb = qp0 + rowbase + tid;
      float s = 0.f;
#pragma unroll
      for (int s2 = 0; s2 < NSL; ++s2) s += ld_f(qb + (size_t)s2 * NN);
      out[rowbase + tid] = s;
    }
  }
}

// ---------------- launcher ----------------

extern "C" void kernel_launch(void* const* d_in, const int* in_sizes, int n_in,
                              void* d_out, int out_size, void* d_ws,
                              size_t ws_size, hipStream_t stream) {
  const float* X_train = (const float*)d_in[0];
  const float* y_train = (const float*)d_in[1];
  const float* X_test = (const float*)d_in[2];
  float* out = (float*)d_out;

  char* w = (char*)d_ws;
  size_t off = 0;
  float* xx_tr = (float*)(w + off); off += NN * 4;
  float* xx_te = (float*)(w + off); off += NN * 4;
  double* rho_s = (double*)(w + off); off += (size_t)NITER * 256 * 8;
  double* mu_s = (double*)(w + off); off += (size_t)NITER * 256 * 8;
  unsigned* bar = (unsigned*)(w + off); off += 4096;  // 2 parity sets + gen
  off = (off + 255) & ~(size_t)255;
  float* qp0 = (float*)(w + off); off += (size_t)NSL * NN * 4;  // 512KB
  size_t need0 = off;
  float* qp1 = (float*)(w + off); off += (size_t)NSL * NN * 4;  // 512KB
  size_t need1 = off;

  int db = (ws_size >= need1) ? 1 : 0;
  if (ws_size < need0) return;  // ~1.5MB; ws >= ~2.3MB proven (R13-R28 db)
  if (!db) qp1 = qp0;

  setup_zero<<<4, 256, 0, stream>>>(bar);
  row_norms<<<NN / 256, 256, 0, stream>>>(X_train, xx_tr);
  row_norms<<<NN / 256, 256, 0, stream>>>(X_test, xx_te);

  cg_persist<<<NBLK, 1024, 0, stream>>>(X_train, X_test, xx_tr, xx_te,
                                        y_train, qp0, qp1, rho_s, mu_s, bar,
                                        out, db);
}